// Round 6
// baseline (455.820 us; speedup 1.0000x reference)
//
#include <hip/hip_runtime.h>
#include <math.h>

// TreeLSTM, complete binary tree N = 2^15-1 (implicit: children(i)=2i+1,2i+2).
// Round 6: dispatch-count attack.
//  - bulk: 1 block per 64-node m-tile computes ALL 1024 gate cols; x staged
//    once to LDS (fp32->bf16 inline), W_ih fragments direct global->VGPR (L2).
//  - levels 13..10: per-level kernels (R5 structure, c now bf16).
//  - levels 9..0: ONE kernel, 64 co-resident blocks, device-scope atomic
//    barrier between levels (R4 showed cg::sync@512blk = 65us; 64-block
//    hand-rolled should be ~1-3us).
//  - c stored bf16 (absmax measured 0.0 -> large precision margin).

#define N_NODES 32767
#define N_LEAF0 16383
#define IN_C    512
#define H_C     256

typedef __bf16 bf16x8 __attribute__((ext_vector_type(8)));
typedef __bf16 bf16x4 __attribute__((ext_vector_type(4)));
typedef float  f32x4  __attribute__((ext_vector_type(4)));

__device__ __forceinline__ void gload_lds16(const void* g, void* l) {
    __builtin_amdgcn_global_load_lds(
        (const __attribute__((address_space(1))) unsigned int*)g,
        (__attribute__((address_space(3))) unsigned int*)l,
        16, 0, 0);
}

__device__ __forceinline__ float fast_rcp(float x) { return __builtin_amdgcn_rcpf(x); }
__device__ __forceinline__ float sigm(float x)     { return fast_rcp(1.f + __expf(-x)); }
__device__ __forceinline__ float tanh_fast(float x){ return 2.f * fast_rcp(1.f + __expf(-2.f * x)) - 1.f; }

// ---- merged weight conversion: W_ih*1.0 and W_hh*0.5 -> bf16 ----
__global__ __launch_bounds__(256)
void conv_weights(const float* __restrict__ wih, const float* __restrict__ whh,
                  __bf16* __restrict__ wihb, __bf16* __restrict__ whh2)
{
    const int i = blockIdx.x * 256 + threadIdx.x;   // n8 total = 65536 + 32768
    const float* src; __bf16* dst; float scale; int j;
    if (i < 65536) { src = wih; dst = wihb; scale = 1.0f; j = i; }
    else           { src = whh; dst = whh2; scale = 0.5f; j = i - 65536; }
    const float4* s4 = (const float4*)src;
    const float4 a = s4[2 * j];
    const float4 b = s4[2 * j + 1];
    bf16x8 o;
    o[0] = (__bf16)(scale * a.x); o[1] = (__bf16)(scale * a.y);
    o[2] = (__bf16)(scale * a.z); o[3] = (__bf16)(scale * a.w);
    o[4] = (__bf16)(scale * b.x); o[5] = (__bf16)(scale * b.y);
    o[6] = (__bf16)(scale * b.z); o[7] = (__bf16)(scale * b.w);
    *(bf16x8*)(dst + 8 * j) = o;
}

// ---- bulk: acc = x @ W_ih^T, all nodes, all 1024 gate cols per block. ----
// grid = 512 blocks x 64 rows. LDS: x-tile [16 kc][64 rows][32 k] bf16 (64 KB).
// Wave w handles col-slabs {w, w+4, w+8, w+12}; slab s covers cols via
// grow = ni*256 + s*16 + l15  => lane owns all 4 gates (ni=q) of CH = s*16+l15.
__global__ __launch_bounds__(256, 2)
void bulk_xw(const float* __restrict__ x,
             const __bf16* __restrict__ wihb,
             const float* __restrict__ b_ih,
             const float* __restrict__ b_hh,
             __bf16* __restrict__ hb,
             __bf16* __restrict__ cb_,
             __bf16* __restrict__ gx)
{
    __shared__ __bf16 As[16 * 64 * 32];   // 64 KB

    const int t    = threadIdx.x;
    const int lane = t & 63;
    const int wv   = t >> 6;
    const int quad = lane >> 4;
    const int l15  = lane & 15;
    const int m0   = blockIdx.x * 64;

    // ---- stage x tile once: thread = row t>>2, 128 k-elems ----
    {
        const int r  = t >> 2;
        const int ks = (t & 3) * 128;
        const int node = min(m0 + r, N_NODES - 1);
        const float* xr = x + (size_t)node * IN_C + ks;
#pragma unroll
        for (int j = 0; j < 16; ++j) {
            const int k = ks + j * 8;
            const float4 a = *(const float4*)(xr + j * 8);
            const float4 b = *(const float4*)(xr + j * 8 + 4);
            bf16x8 o;
            o[0] = (__bf16)a.x; o[1] = (__bf16)a.y; o[2] = (__bf16)a.z; o[3] = (__bf16)a.w;
            o[4] = (__bf16)b.x; o[5] = (__bf16)b.y; o[6] = (__bf16)b.z; o[7] = (__bf16)b.w;
            *(bf16x8*)(As + (k >> 5) * 2048 + r * 32 + (k & 31)) = o;
        }
    }
    __syncthreads();

    for (int sp = 0; sp < 4; ++sp) {
        const int s  = sp * 4 + wv;          // col-slab 0..15
        const int CH = s * 16 + l15;
        float bs[4];
#pragma unroll
        for (int q = 0; q < 4; ++q) bs[q] = b_ih[q * H_C + CH] + b_hh[q * H_C + CH];

        f32x4 acc[4][4];
#pragma unroll
        for (int mi = 0; mi < 4; ++mi)
#pragma unroll
            for (int ni = 0; ni < 4; ++ni) acc[mi][ni] = (f32x4)0.f;

#pragma unroll 4
        for (int kc = 0; kc < 16; ++kc) {
            bf16x8 af[4], bfr[4];
#pragma unroll
            for (int mi = 0; mi < 4; ++mi)
                af[mi] = *(const bf16x8*)(As + kc * 2048 + (mi * 16 + l15) * 32 + quad * 8);
#pragma unroll
            for (int ni = 0; ni < 4; ++ni) {
                const int grow = ni * 256 + s * 16 + l15;
                bfr[ni] = *(const bf16x8*)(wihb + (size_t)grow * IN_C + kc * 32 + quad * 8);
            }
#pragma unroll
            for (int mi = 0; mi < 4; ++mi)
#pragma unroll
                for (int ni = 0; ni < 4; ++ni)
                    acc[mi][ni] = __builtin_amdgcn_mfma_f32_16x16x32_bf16(
                        af[mi], bfr[ni], acc[mi][ni], 0, 0, 0);
        }

        // epilogue for this slab
#pragma unroll
        for (int mi = 0; mi < 4; ++mi) {
#pragma unroll
            for (int r = 0; r < 4; ++r) {
                const int m = m0 + mi * 16 + quad * 4 + r;
                if (m >= N_NODES) continue;
                if (m >= N_LEAF0) {
                    const float gi = sigm(acc[mi][0][r] + bs[0]);
                    const float gg = tanh_fast(acc[mi][2][r] + bs[2]);
                    const float go = sigm(acc[mi][3][r] + bs[3]);
                    const float cn = gi * gg;
                    const float hn = go * tanh_fast(cn);
                    cb_[(size_t)m * H_C + CH] = (__bf16)cn;
                    hb[(size_t)m * H_C + CH] = (__bf16)hn;
                } else {
                    bf16x4 g4;
#pragma unroll
                    for (int q = 0; q < 4; ++q) g4[q] = (__bf16)acc[mi][q][r];
                    *(bf16x4*)(gx + (size_t)m * 1024 + CH * 4) = g4;
                }
            }
        }
    }
}

// ---- per-level kernel (levels 13..10): R5 structure, c in bf16 ----
__global__ __launch_bounds__(256)
void level_hw(const __bf16* __restrict__ whh2,
              const float* __restrict__ b_ih,
              const float* __restrict__ b_hh,
              const __bf16* __restrict__ gx,
              __bf16* __restrict__ hb,
              __bf16* __restrict__ cb_,
              int lo, int n)
{
    __shared__ __bf16 Bfull[8 * 128 * 32];   // 64 KB

    const int t    = threadIdx.x;
    const int lane = t & 63;
    const int wv   = t >> 6;
    const int wm   = wv >> 1;
    const int wn   = wv & 1;
    const int quad = lane >> 4;
    const int l15  = lane & 15;
    const int bx   = blockIdx.x;
    const int cb   = bx & 7;
    const int m0   = (bx >> 3) * 128;

#pragma unroll
    for (int kc = 0; kc < 8; ++kc) {
#pragma unroll
        for (int e = 0; e < 2; ++e) {
            const int chunk = wv * 2 + e;
            const int nl    = chunk * 16 + (lane >> 2);
            const int q     = (nl >> 4) & 3;
            const int cc    = (nl & 15) + ((nl >> 6) << 4);
            const int grow  = q * H_C + cb * 32 + cc;
            const void* g = (const char*)(whh2 + grow * H_C + kc * 32) + (lane & 3) * 16;
            gload_lds16(g, (char*)Bfull + kc * 8192 + chunk * 1024);
        }
    }
    __syncthreads();

    f32x4 acc[4][4];
#pragma unroll
    for (int mi = 0; mi < 4; ++mi)
#pragma unroll
        for (int ni = 0; ni < 4; ++ni) acc[mi][ni] = (f32x4)0.f;

    size_t abase[4];
#pragma unroll
    for (int mi = 0; mi < 4; ++mi) {
        const int node = lo + m0 + wm * 64 + mi * 16 + l15;
        abase[mi] = (size_t)(2 * node + 1) * H_C;
    }

#pragma unroll
    for (int kc = 0; kc < 16; ++kc) {
        bf16x8 af[4], bfr[4];
#pragma unroll
        for (int mi = 0; mi < 4; ++mi)
            af[mi] = *(const bf16x8*)(hb + abase[mi] + kc * 32 + quad * 8);
#pragma unroll
        for (int ni = 0; ni < 4; ++ni)
            bfr[ni] = *(const bf16x8*)(Bfull + (kc & 7) * 4096 +
                                       (wn * 64 + ni * 16 + l15) * 32 + quad * 8);
#pragma unroll
        for (int mi = 0; mi < 4; ++mi)
#pragma unroll
            for (int ni = 0; ni < 4; ++ni)
                acc[mi][ni] = __builtin_amdgcn_mfma_f32_16x16x32_bf16(
                    af[mi], bfr[ni], acc[mi][ni], 0, 0, 0);
    }

    const int CH = cb * 32 + wn * 16 + l15;
    const float bs0 = b_ih[0 * H_C + CH] + b_hh[0 * H_C + CH];
    const float bs1 = b_ih[1 * H_C + CH] + b_hh[1 * H_C + CH];
    const float bs2 = b_ih[2 * H_C + CH] + b_hh[2 * H_C + CH];
    const float bs3 = b_ih[3 * H_C + CH] + b_hh[3 * H_C + CH];

#pragma unroll
    for (int mi = 0; mi < 4; ++mi) {
#pragma unroll
        for (int r = 0; r < 4; ++r) {
            const int m = m0 + wm * 64 + mi * 16 + quad * 4 + r;
            if (m < n) {
                const int node = lo + m;
                const bf16x4 g4 = *(const bf16x4*)(gx + (size_t)node * 1024 + CH * 4);
                const float gi = sigm(acc[mi][0][r] + (float)g4[0] + bs0);
                const float gf = sigm(acc[mi][1][r] + (float)g4[1] + bs1);
                const float gt = tanh_fast(acc[mi][2][r] + (float)g4[2] + bs2);
                const float go = sigm(acc[mi][3][r] + (float)g4[3] + bs3);
                const float mc = 0.5f * ((float)cb_[(size_t)(2 * node + 1) * H_C + CH] +
                                         (float)cb_[(size_t)(2 * node + 2) * H_C + CH]);
                const float cn = gf * mc + gi * gt;
                const float hn = go * tanh_fast(cn);
                cb_[(size_t)node * H_C + CH] = (__bf16)cn;
                hb[(size_t)node * H_C + CH] = (__bf16)hn;
            }
        }
    }
}

// ---- levels 9..0 in ONE kernel: 64 blocks (all co-resident), atomic barrier
// between levels. slab = b&7 (128 gate cols), mg = b>>3 (64-row m-group).
// A and B both direct from global (L2-hot). No LDS at all.
__global__ __launch_bounds__(256)
void levels_tail(const __bf16* __restrict__ whh2,
                 const float* __restrict__ b_ih,
                 const float* __restrict__ b_hh,
                 const __bf16* __restrict__ gx,
                 __bf16* __restrict__ hb,
                 __bf16* __restrict__ cb_,
                 int* __restrict__ bar)
{
    const int t    = threadIdx.x;
    const int lane = t & 63;
    const int wv   = t >> 6;
    const int wm   = wv >> 1;
    const int wn   = wv & 1;
    const int quad = lane >> 4;
    const int l15  = lane & 15;
    const int b    = blockIdx.x;
    const int slab = b & 7;
    const int mg   = b >> 3;

    const int CH = slab * 32 + wn * 16 + l15;
    const float bs0 = b_ih[0 * H_C + CH] + b_hh[0 * H_C + CH];
    const float bs1 = b_ih[1 * H_C + CH] + b_hh[1 * H_C + CH];
    const float bs2 = b_ih[2 * H_C + CH] + b_hh[2 * H_C + CH];
    const float bs3 = b_ih[3 * H_C + CH] + b_hh[3 * H_C + CH];

    int target = 0;

    for (int d = 9; d >= 0; --d) {
        const int n  = 1 << d;
        const int lo = n - 1;
        if (mg * 64 < n) {
            const int m0 = mg * 64;

            f32x4 acc[2][4];
#pragma unroll
            for (int mi = 0; mi < 2; ++mi)
#pragma unroll
                for (int ni = 0; ni < 4; ++ni) acc[mi][ni] = (f32x4)0.f;

            size_t abase[2];
#pragma unroll
            for (int mi = 0; mi < 2; ++mi) {
                const int node = lo + m0 + wm * 32 + mi * 16 + l15;
                abase[mi] = (size_t)(2 * node + 1) * H_C;
            }

#pragma unroll 4
            for (int kc = 0; kc < 16; ++kc) {
                bf16x8 af[2], bfr[4];
#pragma unroll
                for (int mi = 0; mi < 2; ++mi)
                    af[mi] = *(const bf16x8*)(hb + abase[mi] + kc * 32 + quad * 8);
#pragma unroll
                for (int ni = 0; ni < 4; ++ni) {
                    const int grow = ni * H_C + CH;
                    bfr[ni] = *(const bf16x8*)(whh2 + (size_t)grow * H_C +
                                               (kc & 7) * 32 + quad * 8);
                }
#pragma unroll
                for (int mi = 0; mi < 2; ++mi)
#pragma unroll
                    for (int ni = 0; ni < 4; ++ni)
                        acc[mi][ni] = __builtin_amdgcn_mfma_f32_16x16x32_bf16(
                            af[mi], bfr[ni], acc[mi][ni], 0, 0, 0);
            }

#pragma unroll
            for (int mi = 0; mi < 2; ++mi) {
#pragma unroll
                for (int r = 0; r < 4; ++r) {
                    const int m = m0 + wm * 32 + mi * 16 + quad * 4 + r;
                    if (m < n) {
                        const int node = lo + m;
                        const bf16x4 g4 = *(const bf16x4*)(gx + (size_t)node * 1024 + CH * 4);
                        const float gi = sigm(acc[mi][0][r] + (float)g4[0] + bs0);
                        const float gf = sigm(acc[mi][1][r] + (float)g4[1] + bs1);
                        const float gt = tanh_fast(acc[mi][2][r] + (float)g4[2] + bs2);
                        const float go = sigm(acc[mi][3][r] + (float)g4[3] + bs3);
                        const float mc = 0.5f * ((float)cb_[(size_t)(2 * node + 1) * H_C + CH] +
                                                 (float)cb_[(size_t)(2 * node + 2) * H_C + CH]);
                        const float cn = gf * mc + gi * gt;
                        const float hn = go * tanh_fast(cn);
                        cb_[(size_t)node * H_C + CH] = (__bf16)cn;
                        hb[(size_t)node * H_C + CH] = (__bf16)hn;
                    }
                }
            }
        }

        if (d > 0) {
            // device-scope barrier across the 64 co-resident blocks
            __syncthreads();                 // drains this block's stores (vmcnt 0)
            target += 64;
            if (t == 0) {
                __threadfence();             // release: write back L2
                atomicAdd(bar, 1);
                while (__hip_atomic_load(bar, __ATOMIC_RELAXED,
                                         __HIP_MEMORY_SCOPE_AGENT) < target)
                    __builtin_amdgcn_s_sleep(8);
                __threadfence();             // acquire: invalidate stale caches
            }
            __syncthreads();
        }
    }
}

// ---- pooled mean + fc ----
__global__ __launch_bounds__(256)
void reduce_rows(const __bf16* __restrict__ hb, float* __restrict__ part)
{
    const int tcol = threadIdx.x;
    const int b = blockIdx.x;
    float s = 0.f;
    for (int r = 0; r < 128; ++r) {
        const int row = b * 128 + r;
        if (row < N_NODES) s += (float)hb[(size_t)row * H_C + tcol];
    }
    part[b * H_C + tcol] = s;
}

__global__ __launch_bounds__(256)
void reduce_final(const float* __restrict__ part,
                  const float* __restrict__ W_fc,
                  const float* __restrict__ b_fc,
                  float* __restrict__ out)
{
    __shared__ float sm[256];
    const int t = threadIdx.x;
    float s = 0.f;
    for (int j = 0; j < 256; ++j) s += part[j * H_C + t];
    s = s * (1.0f / (float)N_NODES) * W_fc[t];
    sm[t] = s;
    __syncthreads();
    for (int st = 128; st > 0; st >>= 1) {
        if (t < st) sm[t] += sm[t + st];
        __syncthreads();
    }
    if (t == 0) out[0] = sm[0] + b_fc[0];
}

extern "C" void kernel_launch(void* const* d_in, const int* in_sizes, int n_in,
                              void* d_out, int out_size, void* d_ws, size_t ws_size,
                              hipStream_t stream)
{
    const float* x    = (const float*)d_in[0];
    const float* W_ih = (const float*)d_in[2];
    const float* W_hh = (const float*)d_in[3];
    const float* b_ih = (const float*)d_in[4];
    const float* b_hh = (const float*)d_in[5];
    const float* W_fc = (const float*)d_in[6];
    const float* b_fc = (const float*)d_in[7];
    float* out = (float*)d_out;

    char* w = (char*)d_ws;
    __bf16* hb   = (__bf16*)w;  w += (size_t)N_NODES * H_C * 2;       // 16.78 MB
    __bf16* cb_  = (__bf16*)w;  w += (size_t)N_NODES * H_C * 2;       // 16.78 MB
    __bf16* gx   = (__bf16*)w;  w += (size_t)N_LEAF0 * 1024 * 2;      // 33.55 MB
    __bf16* wihb = (__bf16*)w;  w += (size_t)4 * H_C * IN_C * 2;      // 1.05 MB
    __bf16* whh2 = (__bf16*)w;  w += (size_t)4 * H_C * H_C * 2;       // 0.52 MB
    float*  part = (float*)w;   w += (size_t)256 * H_C * 4;           // 0.26 MB
    int*    bar  = (int*)w;

    hipMemsetAsync(bar, 0, sizeof(int), stream);

    conv_weights<<<384, 256, 0, stream>>>(W_ih, W_hh, wihb, whh2);

    bulk_xw<<<512, 256, 0, stream>>>(x, wihb, b_ih, b_hh, hb, cb_, gx);

    for (int d = 13; d >= 10; --d) {
        const int n  = 1 << d;
        const int lo = n - 1;
        const int nm = n / 128;
        level_hw<<<8 * nm, 256, 0, stream>>>(whh2, b_ih, b_hh, gx, hb, cb_, lo, n);
    }

    levels_tail<<<64, 256, 0, stream>>>(whh2, b_ih, b_hh, gx, hb, cb_, bar);

    reduce_rows<<<256, 256, 0, stream>>>(hb, part);
    reduce_final<<<1, 256, 0, stream>>>(part, W_fc, b_fc, out);
}